// Round 9
// baseline (1389.222 us; speedup 1.0000x reference)
//
#include <hip/hip_runtime.h>

#define BATCH   16
#define NPTS    4096
#define NPOINT  1024
#define NSAMPLE 32
#define NSITES  (BATCH*NPOINT*NSAMPLE)   // 524288

// ---------------- workspace layout (bytes) ----------------
// nxyz : 0        (196608)
// gidx : 196608   (2097152)
// psum : 2293760  (512*64*4 = 131072)
// psq  : 2424832  (131072)
// aff0 : 2555904  (128 f = 512)   aff = {a[64], c[64]}: act = relu(a*x+c)
// aff1 : 2556416  (512)
// aff2 : 2556928  (512)
// xbuf : 2557440  (64 MB)  -> total ~69.7 MB

// ---------------- DPP wave-64 max (f32), broadcast via readlane ----------
__device__ __forceinline__ float wave_max_bcast(float x) {
    int v = __float_as_int(x);
    int t;
    t = __builtin_amdgcn_update_dpp(v, v, 0x111, 0xf, 0xf, false);  // row_shr:1
    v = __float_as_int(fmaxf(__int_as_float(v), __int_as_float(t)));
    t = __builtin_amdgcn_update_dpp(v, v, 0x112, 0xf, 0xf, false);  // row_shr:2
    v = __float_as_int(fmaxf(__int_as_float(v), __int_as_float(t)));
    t = __builtin_amdgcn_update_dpp(v, v, 0x114, 0xf, 0xf, false);  // row_shr:4
    v = __float_as_int(fmaxf(__int_as_float(v), __int_as_float(t)));
    t = __builtin_amdgcn_update_dpp(v, v, 0x118, 0xf, 0xf, false);  // row_shr:8
    v = __float_as_int(fmaxf(__int_as_float(v), __int_as_float(t)));
    t = __builtin_amdgcn_update_dpp(v, v, 0x142, 0xa, 0xf, false);  // row_bcast:15
    v = __float_as_int(fmaxf(__int_as_float(v), __int_as_float(t)));
    t = __builtin_amdgcn_update_dpp(v, v, 0x143, 0xc, 0xf, false);  // row_bcast:31
    v = __float_as_int(fmaxf(__int_as_float(v), __int_as_float(t)));
    return __int_as_float(__builtin_amdgcn_readlane(v, 63));
}

// ============================================================
// 1. FPS: one block/batch, 256 threads (4 WAVES), 16 contiguous pts/thread.
//    r7/r8 established: barrier cost (~450cyc @8 waves) and LDS-pipe
//    serialization (~12cyc/b128 x waves) dominate -> fewer waves wins.
//    Reduce = r5's proven structure scaled to 4 keys. Coord registers pinned
//    via empty asm so the compiler cannot re-sink the LDS reads into the
//    loop (r2/r3 remat pathology). Distance math bit-matches reference
//    (validated rounds 2-8): ((dx*dx+dy*dy)+dz*dz), fminf, first-index ties.
// ============================================================
__global__ __launch_bounds__(256, 1) void fps_kernel(
    const float* __restrict__ xyz,   // (B,3,N)
    float* __restrict__ nxyz,        // (B,S,3)
    float* __restrict__ out0)        // (B,3,S)
{
    __shared__ float sx[NPTS], sy[NPTS], sz[NPTS];
    __shared__ int   s_sel[NPOINT];
    __shared__ unsigned long long redK[2][4];

    const int b = blockIdx.x;
    const int t = threadIdx.x;
    const int wave = t >> 6, lane = t & 63;
    const float* xb = xyz + (size_t)b * 3 * NPTS;

    for (int i = t; i < NPTS; i += 256) {
        sx[i] = xb[i]; sy[i] = xb[NPTS+i]; sz[i] = xb[2*NPTS+i];
    }
    __syncthreads();

    const int base = t * 16;
    float px[16], py[16], pz[16], dist[16];
    #pragma unroll
    for (int j = 0; j < 16; ++j) {
        px[j] = sx[base+j]; py[j] = sy[base+j]; pz[j] = sz[base+j];
        // pin into VGPRs: forbids the scheduler from sinking these LDS reads
        // back into the 1024-iter loop (r2/r3 showed it will otherwise).
        asm volatile("" : "+v"(px[j]), "+v"(py[j]), "+v"(pz[j]));
        dist[j] = 1e10f;
    }

    int far = 0;
    float cx = sx[0], cy = sy[0], cz = sz[0];
    for (int it = 0; it < NPOINT; ++it) {
        if (t == 0) s_sel[it] = far;
        #pragma unroll
        for (int j = 0; j < 16; ++j) {
            const float dx = __fsub_rn(px[j], cx);
            const float dy = __fsub_rn(py[j], cy);
            const float dz = __fsub_rn(pz[j], cz);
            const float d  = __fadd_rn(__fadd_rn(__fmul_rn(dx,dx), __fmul_rn(dy,dy)),
                                       __fmul_rn(dz,dz));
            dist[j] = fminf(dist[j], d);
        }
        // per-thread first-max tree (strict > : earlier index wins ties)
        float w0[8]; int j0[8];
        #pragma unroll
        for (int k = 0; k < 8; ++k) {
            const bool c = dist[2*k+1] > dist[2*k];
            w0[k] = c ? dist[2*k+1] : dist[2*k];
            j0[k] = c ? 2*k+1 : 2*k;
        }
        float w1[4]; int j1[4];
        #pragma unroll
        for (int k = 0; k < 4; ++k) {
            const bool c = w0[2*k+1] > w0[2*k];
            w1[k] = c ? w0[2*k+1] : w0[2*k];
            j1[k] = c ? j0[2*k+1] : j0[2*k];
        }
        float w2[2]; int j2[2];
        #pragma unroll
        for (int k = 0; k < 2; ++k) {
            const bool c = w1[2*k+1] > w1[2*k];
            w2[k] = c ? w1[2*k+1] : w1[2*k];
            j2[k] = c ? j1[2*k+1] : j1[2*k];
        }
        float bm; int bj;
        { const bool c = w2[1] > w2[0]; bm = c ? w2[1] : w2[0]; bj = c ? j2[1] : j2[0]; }
        // DPP wave max, uniform broadcast
        const float M = wave_max_bcast(bm);
        // lowest matching lane == smallest global index (contiguous ownership)
        const unsigned long long mask = __ballot(bm == M);
        const int wl = __ffsll((long long)mask) - 1;
        const int par = it & 1;
        if (lane == wl) {
            const unsigned idxg = (unsigned)(base + bj);
            redK[par][wave] = ((unsigned long long)__float_as_uint(bm) << 32)
                              | (unsigned)(~idxg);
        }
        __syncthreads();
        // register compare tree over the 4 wave keys (uniform LDS reads)
        const unsigned long long k0 = redK[par][0], k1 = redK[par][1];
        const unsigned long long k2 = redK[par][2], k3 = redK[par][3];
        const unsigned long long a0 = (k1 > k0) ? k1 : k0;
        const unsigned long long a1 = (k3 > k2) ? k3 : k2;
        const unsigned long long km = (a1 > a0) ? a1 : a0;
        far = (int)((~(unsigned)km) & (NPTS-1));
        cx = sx[far]; cy = sy[far]; cz = sz[far];
    }
    __syncthreads();
    for (int s = t; s < NPOINT; s += 256) {
        const int id = s_sel[s];
        const float x = sx[id], y = sy[id], z = sz[id];
        nxyz[((size_t)b*NPOINT + s)*3 + 0] = x;
        nxyz[((size_t)b*NPOINT + s)*3 + 1] = y;
        nxyz[((size_t)b*NPOINT + s)*3 + 2] = z;
        out0[(size_t)b*3*NPOINT + 0*NPOINT + s] = x;
        out0[(size_t)b*3*NPOINT + 1*NPOINT + s] = y;
        out0[(size_t)b*3*NPOINT + 2*NPOINT + s] = z;
    }
}

// ============================================================
// 2. Ball query (validated bit-exact rounds 2-8 — unchanged).
// ============================================================
__global__ __launch_bounds__(256) void ball_kernel(
    const float* __restrict__ xyz, const float* __restrict__ nxyz,
    int* __restrict__ gidx)
{
    __shared__ float sx[NPTS], sy[NPTS], sz[NPTS];
    const int b  = blockIdx.x >> 4;
    const int sg = blockIdx.x & 15;
    const int t = threadIdx.x;
    const int wave = t >> 6, lane = t & 63;
    const float* xb = xyz + (size_t)b * 3 * NPTS;
    for (int i = t; i < NPTS; i += 256) {
        sx[i] = xb[i]; sy[i] = xb[NPTS+i]; sz[i] = xb[2*NPTS+i];
    }
    __syncthreads();
    const unsigned long long lt = (1ull << lane) - 1ull;

    for (int q = wave; q < 64; q += 4) {
        const int s = sg*64 + q;
        const size_t bs = (size_t)b*NPOINT + s;
        const float cx = nxyz[bs*3+0], cy = nxyz[bs*3+1], cz = nxyz[bs*3+2];
        const float ss = __fadd_rn(__fadd_rn(__fmul_rn(cx,cx), __fmul_rn(cy,cy)),
                                   __fmul_rn(cz,cz));
        int* out = gidx + bs*NSAMPLE;
        int cnt = 0;
        int firstIdx = NPTS;
        for (int ch = 0; ch < NPTS/64 && cnt < NSAMPLE; ++ch) {
            const int pi = ch*64 + lane;
            const float qx = sx[pi], qy = sy[pi], qz = sz[pi];
            const float dot = fmaf(cz, qz, fmaf(cy, qy, __fmul_rn(cx, qx)));
            const float sn  = __fadd_rn(__fadd_rn(__fmul_rn(qx,qx), __fmul_rn(qy,qy)),
                                        __fmul_rn(qz,qz));
            const float d   = __fadd_rn(__fadd_rn(__fmul_rn(-2.0f,dot), ss), sn);
            const bool pred = !(d > 0.04f);
            const unsigned long long m = __ballot(pred);
            if (pred) {
                const int pos = cnt + __popcll(m & lt);
                if (pos == 0) firstIdx = pi;
                if (pos < NSAMPLE) out[pos] = pi;
            }
            cnt += (int)__popcll(m);
        }
        if (cnt < NSAMPLE) {
            #pragma unroll
            for (int off = 32; off >= 1; off >>= 1) {
                const int oi = __shfl_xor(firstIdx, off);
                firstIdx = (oi < firstIdx) ? oi : firstIdx;
            }
            for (int p = cnt + lane; p < NSAMPLE; p += 64) out[p] = firstIdx;
        }
    }
}

// ---------------- feature gather (9 ch per site) ----------------
__device__ __forceinline__ void gather_feat(
    const float* __restrict__ xyz, const float* __restrict__ pts,
    const int* __restrict__ gidx, const float* __restrict__ nxyz,
    int v, float4 f[9])
{
    const int site = v * 4;
    const int bs = site >> 5;
    const int b  = bs >> 10;
    const int4 idx = *reinterpret_cast<const int4*>(gidx + site);
    const float* xb = xyz + (size_t)b*3*NPTS;
    const float* pb = pts + (size_t)b*6*NPTS;
    const float cx = nxyz[(size_t)bs*3+0];
    const float cy = nxyz[(size_t)bs*3+1];
    const float cz = nxyz[(size_t)bs*3+2];
    f[0] = make_float4(xb[idx.x]-cx, xb[idx.y]-cx, xb[idx.z]-cx, xb[idx.w]-cx);
    f[1] = make_float4(xb[NPTS+idx.x]-cy, xb[NPTS+idx.y]-cy, xb[NPTS+idx.z]-cy, xb[NPTS+idx.w]-cy);
    f[2] = make_float4(xb[2*NPTS+idx.x]-cz, xb[2*NPTS+idx.y]-cz, xb[2*NPTS+idx.z]-cz, xb[2*NPTS+idx.w]-cz);
    #pragma unroll
    for (int c = 0; c < 6; ++c)
        f[3+c] = make_float4(pb[c*NPTS+idx.x], pb[c*NPTS+idx.y], pb[c*NPTS+idx.z], pb[c*NPTS+idx.w]);
}

// ============================================================
// 3. conv0: ONE gather pass -> raw conv0 (W0,b0) stored + stats partials.
// ============================================================
__global__ __launch_bounds__(256) void conv0s_kernel(
    const float* __restrict__ xyz, const float* __restrict__ pts,
    const int* __restrict__ gidx, const float* __restrict__ nxyz,
    const float* __restrict__ W, const float* __restrict__ bias,
    float* __restrict__ xout, float* __restrict__ psum, float* __restrict__ psq)
{
    const int t = threadIdx.x;
    const int v = blockIdx.x*256 + t;        // 512 blocks -> v < 131072
    const int site = v * 4;
    float4 f[9];
    gather_feat(xyz, pts, gidx, nxyz, v, f);
    float acc[32], accq[32];
    #pragma unroll
    for (int o = 0; o < 32; ++o) {
        const float bb = bias[o];
        float4 y = make_float4(bb,bb,bb,bb);
        #pragma unroll
        for (int c = 0; c < 9; ++c) {
            const float w = W[o*9+c];
            y.x = fmaf(w, f[c].x, y.x); y.y = fmaf(w, f[c].y, y.y);
            y.z = fmaf(w, f[c].z, y.z); y.w = fmaf(w, f[c].w, y.w);
        }
        *reinterpret_cast<float4*>(xout + (size_t)o*NSITES + site) = y;  // RAW
        acc[o]  = (y.x + y.y) + (y.z + y.w);
        accq[o] = (y.x*y.x + y.y*y.y) + (y.z*y.z + y.w*y.w);
    }
    __shared__ float ls[4][32], lq[4][32];
    const int wave = t>>6, lane = t&63;
    #pragma unroll
    for (int o = 0; o < 32; ++o) {
        float s1 = acc[o], q1 = accq[o];
        #pragma unroll
        for (int off = 32; off >= 1; off >>= 1) {
            s1 += __shfl_xor(s1, off);
            q1 += __shfl_xor(q1, off);
        }
        if (lane == 0) { ls[wave][o] = s1; lq[wave][o] = q1; }
    }
    __syncthreads();
    if (t < 32) {
        psum[blockIdx.x*64 + t] = (ls[0][t]+ls[1][t]) + (ls[2][t]+ls[3][t]);
        psq [blockIdx.x*64 + t] = (lq[0][t]+lq[1][t]) + (lq[2][t]+lq[3][t]);
    }
}

// ============================================================
// 4. fold: partials -> mean/var -> affine {a, c}: act = relu(a*raw + c)
//    Parallel version (r5-proven): 256 threads, 4 parts/channel + LDS combine.
// ============================================================
__global__ void fold_kernel(
    const float* __restrict__ g, const float* __restrict__ be,
    const float* __restrict__ psum, const float* __restrict__ psq,
    float* __restrict__ aff, int Cout)
{
    __shared__ float ss[4][64], qq[4][64];
    const int t = threadIdx.x;           // 256
    const int ch = t & 63, part = t >> 6;
    float s = 0.f, q = 0.f;
    for (int i = part; i < 512; i += 4) {
        s += psum[i*64 + ch];
        q += psq [i*64 + ch];
    }
    ss[part][ch] = s; qq[part][ch] = q;
    __syncthreads();
    if (t < Cout) {
        s = (ss[0][t]+ss[1][t]) + (ss[2][t]+ss[3][t]);
        q = (qq[0][t]+qq[1][t]) + (qq[2][t]+qq[3][t]);
        const float invn = 1.0f / (float)NSITES;
        const float m = s * invn;
        float v2 = fmaxf(q * invn - m*m, 0.f);
        const float a = g[t] * rsqrtf(v2 + 1e-5f);
        aff[t]      = a;
        aff[64 + t] = fmaf(-m, a, be[t]);
    }
}

// ============================================================
// 5. conv1: read raw0, act0 = relu(a0*x+c0) on the fly, conv1 (W1,b1) ->
//    raw1 stored IN PLACE + stats partials.
// ============================================================
__global__ __launch_bounds__(256) void conv1s_kernel(
    const float* x, float* xout,
    const float* __restrict__ aff, const float* __restrict__ W,
    const float* __restrict__ bias,
    float* __restrict__ psum, float* __restrict__ psq)
{
    const int t = threadIdx.x;
    const int v = blockIdx.x*256 + t;
    const int site = v * 4;
    float4 in[32];
    #pragma unroll
    for (int c = 0; c < 32; ++c) {
        float4 r = *reinterpret_cast<const float4*>(x + (size_t)c*NSITES + site);
        const float a = aff[c], cc = aff[64 + c];
        in[c].x = fmaxf(fmaf(a, r.x, cc), 0.f);
        in[c].y = fmaxf(fmaf(a, r.y, cc), 0.f);
        in[c].z = fmaxf(fmaf(a, r.z, cc), 0.f);
        in[c].w = fmaxf(fmaf(a, r.w, cc), 0.f);
    }
    float acc[32], accq[32];
    #pragma unroll
    for (int o = 0; o < 32; ++o) {
        const float bb = bias[o];
        float4 y = make_float4(bb,bb,bb,bb);
        #pragma unroll
        for (int c = 0; c < 32; ++c) {
            const float w = W[o*32+c];
            y.x = fmaf(w, in[c].x, y.x); y.y = fmaf(w, in[c].y, y.y);
            y.z = fmaf(w, in[c].z, y.z); y.w = fmaf(w, in[c].w, y.w);
        }
        *reinterpret_cast<float4*>(xout + (size_t)o*NSITES + site) = y;  // RAW
        acc[o]  = (y.x + y.y) + (y.z + y.w);
        accq[o] = (y.x*y.x + y.y*y.y) + (y.z*y.z + y.w*y.w);
    }
    __shared__ float ls[4][32], lq[4][32];
    const int wave = t>>6, lane = t&63;
    #pragma unroll
    for (int o = 0; o < 32; ++o) {
        float s1 = acc[o], q1 = accq[o];
        #pragma unroll
        for (int off = 32; off >= 1; off >>= 1) {
            s1 += __shfl_xor(s1, off);
            q1 += __shfl_xor(q1, off);
        }
        if (lane == 0) { ls[wave][o] = s1; lq[wave][o] = q1; }
    }
    __syncthreads();
    if (t < 32) {
        psum[blockIdx.x*64 + t] = (ls[0][t]+ls[1][t]) + (ls[2][t]+ls[3][t]);
        psq [blockIdx.x*64 + t] = (lq[0][t]+lq[1][t]) + (lq[2][t]+lq[3][t]);
    }
}

// ============================================================
// 6. conv2 stats: SINGLE pass (was 2 y-passes reading 64MB each).
//    512 blocks x 512 threads x 2 sites/thread; acc[64] in registers
//    (~210 VGPR, 2 waves/SIMD). Reads raw1 once (64MB), act1 on the fly.
// ============================================================
__global__ __launch_bounds__(512, 1) void conv2stats_kernel(
    const float* __restrict__ x, const float* __restrict__ aff,
    const float* __restrict__ W, const float* __restrict__ bias,
    float* __restrict__ psum, float* __restrict__ psq)
{
    const int t = threadIdx.x;
    const int v = blockIdx.x*512 + t;        // 512 blocks -> v < 262144
    const int site = v * 2;
    float2 in[32];
    #pragma unroll
    for (int c = 0; c < 32; ++c) {
        const float2 r = *reinterpret_cast<const float2*>(x + (size_t)c*NSITES + site);
        const float a = aff[c], cc = aff[64 + c];
        in[c].x = fmaxf(fmaf(a, r.x, cc), 0.f);
        in[c].y = fmaxf(fmaf(a, r.y, cc), 0.f);
    }
    float acc[64], accq[64];
    #pragma unroll
    for (int o = 0; o < 64; ++o) {
        const float bb = bias[o];
        float yx = bb, yy = bb;
        #pragma unroll
        for (int c = 0; c < 32; ++c) {
            const float w = W[o*32+c];
            yx = fmaf(w, in[c].x, yx);
            yy = fmaf(w, in[c].y, yy);
        }
        acc[o]  = yx + yy;
        accq[o] = yx*yx + yy*yy;
    }
    __shared__ float ls[8][64], lq[8][64];
    const int wave = t>>6, lane = t&63;
    #pragma unroll
    for (int o = 0; o < 64; ++o) {
        float s1 = acc[o], q1 = accq[o];
        #pragma unroll
        for (int off = 32; off >= 1; off >>= 1) {
            s1 += __shfl_xor(s1, off);
            q1 += __shfl_xor(q1, off);
        }
        if (lane == 0) { ls[wave][o] = s1; lq[wave][o] = q1; }
    }
    __syncthreads();
    if (t < 64) {
        psum[blockIdx.x*64 + t] = ((ls[0][t]+ls[1][t]) + (ls[2][t]+ls[3][t]))
                                + ((ls[4][t]+ls[5][t]) + (ls[6][t]+ls[7][t]));
        psq [blockIdx.x*64 + t] = ((lq[0][t]+lq[1][t]) + (lq[2][t]+lq[3][t]))
                                + ((lq[4][t]+lq[5][t]) + (lq[6][t]+lq[7][t]));
    }
}

// ============================================================
// 7. conv2 + affine2 + relu + max over k -> output (B,64,S).
// ============================================================
__global__ __launch_bounds__(256) void conv2max_kernel(
    const float* __restrict__ x, const float* __restrict__ aff1,
    const float* __restrict__ aff2, const float* __restrict__ W,
    const float* __restrict__ bias, float* __restrict__ outp)
{
    const int gt = blockIdx.x*256 + threadIdx.x;
    const int wv = gt >> 6;
    const int lane = gt & 63;
    const int base = wv * 64;
    float in[32];
    #pragma unroll
    for (int c = 0; c < 32; ++c) {
        const float r = x[(size_t)c*NSITES + base + lane];
        in[c] = fmaxf(fmaf(aff1[c], r, aff1[64 + c]), 0.f);
    }
    const int bs = (base + lane) >> 5;
    const int b = bs >> 10, s = bs & 1023;
    float* dst = outp + (size_t)b*64*NPOINT + s;
    for (int o = 0; o < 64; ++o) {
        float z = bias[o];
        #pragma unroll
        for (int c = 0; c < 32; ++c)
            z = fmaf(W[o*32+c], in[c], z);
        float y = fmaxf(fmaf(aff2[o], z, aff2[64 + o]), 0.f);
        #pragma unroll
        for (int off = 16; off >= 1; off >>= 1)
            y = fmaxf(y, __shfl_xor(y, off));
        if ((lane & 31) == 0)
            dst[(size_t)o*NPOINT] = y;
    }
}

// ============================================================
extern "C" void kernel_launch(void* const* d_in, const int* in_sizes, int n_in,
                              void* d_out, int out_size, void* d_ws, size_t ws_size,
                              hipStream_t stream) {
    (void)in_sizes; (void)n_in; (void)out_size; (void)ws_size;
    const float* xyz = (const float*)d_in[0];
    const float* pts = (const float*)d_in[1];
    const float* W0  = (const float*)d_in[2];
    const float* b0  = (const float*)d_in[3];
    const float* g0  = (const float*)d_in[4];
    const float* be0 = (const float*)d_in[5];
    const float* W1  = (const float*)d_in[6];
    const float* b1  = (const float*)d_in[7];
    const float* g1  = (const float*)d_in[8];
    const float* be1 = (const float*)d_in[9];
    const float* W2  = (const float*)d_in[10];
    const float* b2  = (const float*)d_in[11];
    const float* g2  = (const float*)d_in[12];
    const float* be2 = (const float*)d_in[13];
    float* out = (float*)d_out;
    char* ws = (char*)d_ws;
    float* nxyz = (float*)(ws + 0);
    int*   gidx = (int*)  (ws + 196608);
    float* psum = (float*)(ws + 2293760);
    float* psq  = (float*)(ws + 2424832);
    float* aff0 = (float*)(ws + 2555904);
    float* aff1 = (float*)(ws + 2556416);
    float* aff2 = (float*)(ws + 2556928);
    float* xbuf = (float*)(ws + 2557440);

    fps_kernel <<<16,  256, 0, stream>>>(xyz, nxyz, out);
    ball_kernel<<<256, 256, 0, stream>>>(xyz, nxyz, gidx);

    conv0s_kernel<<<512, 256, 0, stream>>>(xyz, pts, gidx, nxyz, W0, b0,
                                           xbuf, psum, psq);
    fold_kernel<<<1, 256, 0, stream>>>(g0, be0, psum, psq, aff0, 32);

    conv1s_kernel<<<512, 256, 0, stream>>>(xbuf, xbuf, aff0, W1, b1, psum, psq);
    fold_kernel<<<1, 256, 0, stream>>>(g1, be1, psum, psq, aff1, 32);

    conv2stats_kernel<<<512, 512, 0, stream>>>(xbuf, aff1, W2, b2, psum, psq);
    fold_kernel<<<1, 256, 0, stream>>>(g2, be2, psum, psq, aff2, 64);

    conv2max_kernel<<<2048, 256, 0, stream>>>(xbuf, aff1, aff2, W2, b2,
                                              out + 49152);
}

// Round 10
// 1071.308 us; speedup vs baseline: 1.2968x; 1.2968x over previous
//
#include <hip/hip_runtime.h>

#define BATCH   16
#define NPTS    4096
#define NPOINT  1024
#define NSAMPLE 32
#define NSITES  (BATCH*NPOINT*NSAMPLE)   // 524288

// ---------------- workspace layout (bytes) ----------------
// nxyz : 0        (196608)
// gidx : 196608   (2097152)
// psum : 2293760  (512*64*4 = 131072)
// psq  : 2424832  (131072)
// aff0 : 2555904  (128 f = 512)   aff = {a[64], c[64]}: act = relu(a*x+c)
// aff1 : 2556416  (512)
// aff2 : 2556928  (512)
// xbuf : 2557440  (64 MB)  -> total ~69.7 MB

// ---------------- DPP wave-64 max (f32), broadcast via readlane ----------
__device__ __forceinline__ float wave_max_bcast(float x) {
    int v = __float_as_int(x);
    int t;
    t = __builtin_amdgcn_update_dpp(v, v, 0x111, 0xf, 0xf, false);  // row_shr:1
    v = __float_as_int(fmaxf(__int_as_float(v), __int_as_float(t)));
    t = __builtin_amdgcn_update_dpp(v, v, 0x112, 0xf, 0xf, false);  // row_shr:2
    v = __float_as_int(fmaxf(__int_as_float(v), __int_as_float(t)));
    t = __builtin_amdgcn_update_dpp(v, v, 0x114, 0xf, 0xf, false);  // row_shr:4
    v = __float_as_int(fmaxf(__int_as_float(v), __int_as_float(t)));
    t = __builtin_amdgcn_update_dpp(v, v, 0x118, 0xf, 0xf, false);  // row_shr:8
    v = __float_as_int(fmaxf(__int_as_float(v), __int_as_float(t)));
    t = __builtin_amdgcn_update_dpp(v, v, 0x142, 0xa, 0xf, false);  // row_bcast:15
    v = __float_as_int(fmaxf(__int_as_float(v), __int_as_float(t)));
    t = __builtin_amdgcn_update_dpp(v, v, 0x143, 0xc, 0xf, false);  // row_bcast:31
    v = __float_as_int(fmaxf(__int_as_float(v), __int_as_float(t)));
    return __int_as_float(__builtin_amdgcn_readlane(v, 63));
}

// ---- u64 max over each 8-lane group (every lane holds key[lane&7]) ------
// 3-step butterfly: quad_perm xor1 (0xB1), quad_perm xor2 (0x4E),
// row_half_mirror (0x141). u64 compare as (hi,lo) u32 pair — monotone since
// hi = f32 bits of d >= 0. All lanes end with max over the 8 keys.
__device__ __forceinline__ unsigned long long grp8_max_u64(unsigned long long k) {
    unsigned lo = (unsigned)k, hi = (unsigned)(k >> 32);
    #define GRP8_STEP(CTRL) { \
        const unsigned lo_o = (unsigned)__builtin_amdgcn_update_dpp((int)lo, (int)lo, CTRL, 0xf, 0xf, true); \
        const unsigned hi_o = (unsigned)__builtin_amdgcn_update_dpp((int)hi, (int)hi, CTRL, 0xf, 0xf, true); \
        const bool gt = (hi_o > hi) || (hi_o == hi && lo_o > lo); \
        hi = gt ? hi_o : hi; lo = gt ? lo_o : lo; }
    GRP8_STEP(0xB1)   // quad_perm [1,0,3,2]
    GRP8_STEP(0x4E)   // quad_perm [2,3,0,1]
    GRP8_STEP(0x141)  // row_half_mirror
    #undef GRP8_STEP
    return ((unsigned long long)hi << 32) | lo;
}

// ============================================================
// 1. FPS: one block/batch, 512 threads, 8 CONTIGUOUS pts/thread in registers
//    (VGPR=40 resident — r4/r5-verified; 16pt/thread remats, r9).
//    Pre-barrier: r5's proven structure (dist update, val+idx tree, DPP wave
//    max, ballot lowest-lane, winner writes u64 key). Post-barrier (NEW):
//    distributed key read — every lane reads redK[lane&7] (ONE ds_read_b64
//    per wave, same-address broadcast) + 3-step DPP group-8 u64 max in
//    registers. Replaces r5's 4x ds_read_b128 per wave (32 b128/iter on one
//    LDS pipe was the largest cost term).
//    Distance math bit-matches reference (validated rounds 2-9).
// ============================================================
__global__ __launch_bounds__(512, 1) void fps_kernel(
    const float* __restrict__ xyz,   // (B,3,N)
    float* __restrict__ nxyz,        // (B,S,3)
    float* __restrict__ out0)        // (B,3,S)
{
    __shared__ float sx[NPTS], sy[NPTS], sz[NPTS];
    __shared__ int   s_sel[NPOINT];
    __shared__ unsigned long long redK[2][8];

    const int b = blockIdx.x;
    const int t = threadIdx.x;
    const int wave = t >> 6, lane = t & 63;
    const float* xb = xyz + (size_t)b * 3 * NPTS;

    for (int i = t; i < NPTS; i += 512) {
        sx[i] = xb[i]; sy[i] = xb[NPTS+i]; sz[i] = xb[2*NPTS+i];
    }
    __syncthreads();

    const int base = t * 8;
    float px[8], py[8], pz[8], dist[8];
    #pragma unroll
    for (int j = 0; j < 8; ++j) {
        px[j] = sx[base+j]; py[j] = sy[base+j]; pz[j] = sz[base+j];
        dist[j] = 1e10f;
    }

    int far = 0;
    float cx = sx[0], cy = sy[0], cz = sz[0];
    for (int it = 0; it < NPOINT; ++it) {
        if (t == 0) s_sel[it] = far;
        #pragma unroll
        for (int j = 0; j < 8; ++j) {
            const float dx = __fsub_rn(px[j], cx);
            const float dy = __fsub_rn(py[j], cy);
            const float dz = __fsub_rn(pz[j], cz);
            const float d  = __fadd_rn(__fadd_rn(__fmul_rn(dx,dx), __fmul_rn(dy,dy)),
                                       __fmul_rn(dz,dz));
            dist[j] = fminf(dist[j], d);
        }
        // per-thread first-max tree (strict > : earlier index wins ties)
        float tv0, tv1, tv2, tv3; int ti0, ti1, ti2, ti3;
        { bool c = dist[1] > dist[0]; tv0 = c ? dist[1] : dist[0]; ti0 = c ? 1 : 0; }
        { bool c = dist[3] > dist[2]; tv1 = c ? dist[3] : dist[2]; ti1 = c ? 3 : 2; }
        { bool c = dist[5] > dist[4]; tv2 = c ? dist[5] : dist[4]; ti2 = c ? 5 : 4; }
        { bool c = dist[7] > dist[6]; tv3 = c ? dist[7] : dist[6]; ti3 = c ? 7 : 6; }
        float nv0, nv1; int ni0, ni1;
        { bool c = tv1 > tv0; nv0 = c ? tv1 : tv0; ni0 = c ? ti1 : ti0; }
        { bool c = tv3 > tv2; nv1 = c ? tv3 : tv2; ni1 = c ? ti3 : ti2; }
        float bm; int bj;
        { bool c = nv1 > nv0; bm = c ? nv1 : nv0; bj = c ? ni1 : ni0; }
        // DPP wave max, uniform broadcast
        const float M = wave_max_bcast(bm);
        // lowest matching lane == smallest global index (contiguous ownership)
        const unsigned long long mask = __ballot(bm == M);
        const int wl = __ffsll((long long)mask) - 1;
        const int par = it & 1;
        if (lane == wl) {
            const unsigned idxg = (unsigned)(base + bj);
            redK[par][wave] = ((unsigned long long)__float_as_uint(M) << 32)
                              | (unsigned)(~idxg);
        }
        __syncthreads();
        // distributed key read: ONE ds_read_b64 per wave (broadcast within
        // 8-lane groups), then in-register DPP butterfly over the group.
        const unsigned long long km = grp8_max_u64(redK[par][lane & 7]);
        far = (int)((~(unsigned)km) & (NPTS-1));
        cx = sx[far]; cy = sy[far]; cz = sz[far];
    }
    __syncthreads();
    for (int s = t; s < NPOINT; s += 512) {
        const int id = s_sel[s];
        const float x = sx[id], y = sy[id], z = sz[id];
        nxyz[((size_t)b*NPOINT + s)*3 + 0] = x;
        nxyz[((size_t)b*NPOINT + s)*3 + 1] = y;
        nxyz[((size_t)b*NPOINT + s)*3 + 2] = z;
        out0[(size_t)b*3*NPOINT + 0*NPOINT + s] = x;
        out0[(size_t)b*3*NPOINT + 1*NPOINT + s] = y;
        out0[(size_t)b*3*NPOINT + 2*NPOINT + s] = z;
    }
}

// ============================================================
// 2. Ball query (validated bit-exact rounds 2-9 — unchanged).
// ============================================================
__global__ __launch_bounds__(256) void ball_kernel(
    const float* __restrict__ xyz, const float* __restrict__ nxyz,
    int* __restrict__ gidx)
{
    __shared__ float sx[NPTS], sy[NPTS], sz[NPTS];
    const int b  = blockIdx.x >> 4;
    const int sg = blockIdx.x & 15;
    const int t = threadIdx.x;
    const int wave = t >> 6, lane = t & 63;
    const float* xb = xyz + (size_t)b * 3 * NPTS;
    for (int i = t; i < NPTS; i += 256) {
        sx[i] = xb[i]; sy[i] = xb[NPTS+i]; sz[i] = xb[2*NPTS+i];
    }
    __syncthreads();
    const unsigned long long lt = (1ull << lane) - 1ull;

    for (int q = wave; q < 64; q += 4) {
        const int s = sg*64 + q;
        const size_t bs = (size_t)b*NPOINT + s;
        const float cx = nxyz[bs*3+0], cy = nxyz[bs*3+1], cz = nxyz[bs*3+2];
        const float ss = __fadd_rn(__fadd_rn(__fmul_rn(cx,cx), __fmul_rn(cy,cy)),
                                   __fmul_rn(cz,cz));
        int* out = gidx + bs*NSAMPLE;
        int cnt = 0;
        int firstIdx = NPTS;
        for (int ch = 0; ch < NPTS/64 && cnt < NSAMPLE; ++ch) {
            const int pi = ch*64 + lane;
            const float qx = sx[pi], qy = sy[pi], qz = sz[pi];
            const float dot = fmaf(cz, qz, fmaf(cy, qy, __fmul_rn(cx, qx)));
            const float sn  = __fadd_rn(__fadd_rn(__fmul_rn(qx,qx), __fmul_rn(qy,qy)),
                                        __fmul_rn(qz,qz));
            const float d   = __fadd_rn(__fadd_rn(__fmul_rn(-2.0f,dot), ss), sn);
            const bool pred = !(d > 0.04f);
            const unsigned long long m = __ballot(pred);
            if (pred) {
                const int pos = cnt + __popcll(m & lt);
                if (pos == 0) firstIdx = pi;
                if (pos < NSAMPLE) out[pos] = pi;
            }
            cnt += (int)__popcll(m);
        }
        if (cnt < NSAMPLE) {
            #pragma unroll
            for (int off = 32; off >= 1; off >>= 1) {
                const int oi = __shfl_xor(firstIdx, off);
                firstIdx = (oi < firstIdx) ? oi : firstIdx;
            }
            for (int p = cnt + lane; p < NSAMPLE; p += 64) out[p] = firstIdx;
        }
    }
}

// ---------------- feature gather (9 ch per site) ----------------
__device__ __forceinline__ void gather_feat(
    const float* __restrict__ xyz, const float* __restrict__ pts,
    const int* __restrict__ gidx, const float* __restrict__ nxyz,
    int v, float4 f[9])
{
    const int site = v * 4;
    const int bs = site >> 5;
    const int b  = bs >> 10;
    const int4 idx = *reinterpret_cast<const int4*>(gidx + site);
    const float* xb = xyz + (size_t)b*3*NPTS;
    const float* pb = pts + (size_t)b*6*NPTS;
    const float cx = nxyz[(size_t)bs*3+0];
    const float cy = nxyz[(size_t)bs*3+1];
    const float cz = nxyz[(size_t)bs*3+2];
    f[0] = make_float4(xb[idx.x]-cx, xb[idx.y]-cx, xb[idx.z]-cx, xb[idx.w]-cx);
    f[1] = make_float4(xb[NPTS+idx.x]-cy, xb[NPTS+idx.y]-cy, xb[NPTS+idx.z]-cy, xb[NPTS+idx.w]-cy);
    f[2] = make_float4(xb[2*NPTS+idx.x]-cz, xb[2*NPTS+idx.y]-cz, xb[2*NPTS+idx.z]-cz, xb[2*NPTS+idx.w]-cz);
    #pragma unroll
    for (int c = 0; c < 6; ++c)
        f[3+c] = make_float4(pb[c*NPTS+idx.x], pb[c*NPTS+idx.y], pb[c*NPTS+idx.z], pb[c*NPTS+idx.w]);
}

// ============================================================
// 3. conv0: ONE gather pass -> raw conv0 (W0,b0) stored + stats partials.
// ============================================================
__global__ __launch_bounds__(256) void conv0s_kernel(
    const float* __restrict__ xyz, const float* __restrict__ pts,
    const int* __restrict__ gidx, const float* __restrict__ nxyz,
    const float* __restrict__ W, const float* __restrict__ bias,
    float* __restrict__ xout, float* __restrict__ psum, float* __restrict__ psq)
{
    const int t = threadIdx.x;
    const int v = blockIdx.x*256 + t;        // 512 blocks -> v < 131072
    const int site = v * 4;
    float4 f[9];
    gather_feat(xyz, pts, gidx, nxyz, v, f);
    float acc[32], accq[32];
    #pragma unroll
    for (int o = 0; o < 32; ++o) {
        const float bb = bias[o];
        float4 y = make_float4(bb,bb,bb,bb);
        #pragma unroll
        for (int c = 0; c < 9; ++c) {
            const float w = W[o*9+c];
            y.x = fmaf(w, f[c].x, y.x); y.y = fmaf(w, f[c].y, y.y);
            y.z = fmaf(w, f[c].z, y.z); y.w = fmaf(w, f[c].w, y.w);
        }
        *reinterpret_cast<float4*>(xout + (size_t)o*NSITES + site) = y;  // RAW
        acc[o]  = (y.x + y.y) + (y.z + y.w);
        accq[o] = (y.x*y.x + y.y*y.y) + (y.z*y.z + y.w*y.w);
    }
    __shared__ float ls[4][32], lq[4][32];
    const int wave = t>>6, lane = t&63;
    #pragma unroll
    for (int o = 0; o < 32; ++o) {
        float s1 = acc[o], q1 = accq[o];
        #pragma unroll
        for (int off = 32; off >= 1; off >>= 1) {
            s1 += __shfl_xor(s1, off);
            q1 += __shfl_xor(q1, off);
        }
        if (lane == 0) { ls[wave][o] = s1; lq[wave][o] = q1; }
    }
    __syncthreads();
    if (t < 32) {
        psum[blockIdx.x*64 + t] = (ls[0][t]+ls[1][t]) + (ls[2][t]+ls[3][t]);
        psq [blockIdx.x*64 + t] = (lq[0][t]+lq[1][t]) + (lq[2][t]+lq[3][t]);
    }
}

// ============================================================
// 4. fold: partials -> mean/var -> affine {a, c}: act = relu(a*raw + c)
//    Parallel version: 256 threads, 4 parts/channel + LDS combine.
// ============================================================
__global__ void fold_kernel(
    const float* __restrict__ g, const float* __restrict__ be,
    const float* __restrict__ psum, const float* __restrict__ psq,
    float* __restrict__ aff, int Cout)
{
    __shared__ float ss[4][64], qq[4][64];
    const int t = threadIdx.x;           // 256
    const int ch = t & 63, part = t >> 6;
    float s = 0.f, q = 0.f;
    for (int i = part; i < 512; i += 4) {
        s += psum[i*64 + ch];
        q += psq [i*64 + ch];
    }
    ss[part][ch] = s; qq[part][ch] = q;
    __syncthreads();
    if (t < Cout) {
        s = (ss[0][t]+ss[1][t]) + (ss[2][t]+ss[3][t]);
        q = (qq[0][t]+qq[1][t]) + (qq[2][t]+qq[3][t]);
        const float invn = 1.0f / (float)NSITES;
        const float m = s * invn;
        float v2 = fmaxf(q * invn - m*m, 0.f);
        const float a = g[t] * rsqrtf(v2 + 1e-5f);
        aff[t]      = a;
        aff[64 + t] = fmaf(-m, a, be[t]);
    }
}

// ============================================================
// 5. conv1: read raw0, act0 = relu(a0*x+c0) on the fly, conv1 (W1,b1) ->
//    raw1 stored IN PLACE + stats partials.
// ============================================================
__global__ __launch_bounds__(256) void conv1s_kernel(
    const float* x, float* xout,
    const float* __restrict__ aff, const float* __restrict__ W,
    const float* __restrict__ bias,
    float* __restrict__ psum, float* __restrict__ psq)
{
    const int t = threadIdx.x;
    const int v = blockIdx.x*256 + t;
    const int site = v * 4;
    float4 in[32];
    #pragma unroll
    for (int c = 0; c < 32; ++c) {
        float4 r = *reinterpret_cast<const float4*>(x + (size_t)c*NSITES + site);
        const float a = aff[c], cc = aff[64 + c];
        in[c].x = fmaxf(fmaf(a, r.x, cc), 0.f);
        in[c].y = fmaxf(fmaf(a, r.y, cc), 0.f);
        in[c].z = fmaxf(fmaf(a, r.z, cc), 0.f);
        in[c].w = fmaxf(fmaf(a, r.w, cc), 0.f);
    }
    float acc[32], accq[32];
    #pragma unroll
    for (int o = 0; o < 32; ++o) {
        const float bb = bias[o];
        float4 y = make_float4(bb,bb,bb,bb);
        #pragma unroll
        for (int c = 0; c < 32; ++c) {
            const float w = W[o*32+c];
            y.x = fmaf(w, in[c].x, y.x); y.y = fmaf(w, in[c].y, y.y);
            y.z = fmaf(w, in[c].z, y.z); y.w = fmaf(w, in[c].w, y.w);
        }
        *reinterpret_cast<float4*>(xout + (size_t)o*NSITES + site) = y;  // RAW
        acc[o]  = (y.x + y.y) + (y.z + y.w);
        accq[o] = (y.x*y.x + y.y*y.y) + (y.z*y.z + y.w*y.w);
    }
    __shared__ float ls[4][32], lq[4][32];
    const int wave = t>>6, lane = t&63;
    #pragma unroll
    for (int o = 0; o < 32; ++o) {
        float s1 = acc[o], q1 = accq[o];
        #pragma unroll
        for (int off = 32; off >= 1; off >>= 1) {
            s1 += __shfl_xor(s1, off);
            q1 += __shfl_xor(q1, off);
        }
        if (lane == 0) { ls[wave][o] = s1; lq[wave][o] = q1; }
    }
    __syncthreads();
    if (t < 32) {
        psum[blockIdx.x*64 + t] = (ls[0][t]+ls[1][t]) + (ls[2][t]+ls[3][t]);
        psq [blockIdx.x*64 + t] = (lq[0][t]+lq[1][t]) + (lq[2][t]+lq[3][t]);
    }
}

// ============================================================
// 6. conv2 stats: SINGLE pass (r9-proven). 512 blocks x 512 threads x
//    2 sites/thread; acc[64] in registers. Reads raw1 once, act1 on the fly.
// ============================================================
__global__ __launch_bounds__(512, 1) void conv2stats_kernel(
    const float* __restrict__ x, const float* __restrict__ aff,
    const float* __restrict__ W, const float* __restrict__ bias,
    float* __restrict__ psum, float* __restrict__ psq)
{
    const int t = threadIdx.x;
    const int v = blockIdx.x*512 + t;        // 512 blocks -> v < 262144
    const int site = v * 2;
    float2 in[32];
    #pragma unroll
    for (int c = 0; c < 32; ++c) {
        const float2 r = *reinterpret_cast<const float2*>(x + (size_t)c*NSITES + site);
        const float a = aff[c], cc = aff[64 + c];
        in[c].x = fmaxf(fmaf(a, r.x, cc), 0.f);
        in[c].y = fmaxf(fmaf(a, r.y, cc), 0.f);
    }
    float acc[64], accq[64];
    #pragma unroll
    for (int o = 0; o < 64; ++o) {
        const float bb = bias[o];
        float yx = bb, yy = bb;
        #pragma unroll
        for (int c = 0; c < 32; ++c) {
            const float w = W[o*32+c];
            yx = fmaf(w, in[c].x, yx);
            yy = fmaf(w, in[c].y, yy);
        }
        acc[o]  = yx + yy;
        accq[o] = yx*yx + yy*yy;
    }
    __shared__ float ls[8][64], lq[8][64];
    const int wave = t>>6, lane = t&63;
    #pragma unroll
    for (int o = 0; o < 64; ++o) {
        float s1 = acc[o], q1 = accq[o];
        #pragma unroll
        for (int off = 32; off >= 1; off >>= 1) {
            s1 += __shfl_xor(s1, off);
            q1 += __shfl_xor(q1, off);
        }
        if (lane == 0) { ls[wave][o] = s1; lq[wave][o] = q1; }
    }
    __syncthreads();
    if (t < 64) {
        psum[blockIdx.x*64 + t] = ((ls[0][t]+ls[1][t]) + (ls[2][t]+ls[3][t]))
                                + ((ls[4][t]+ls[5][t]) + (ls[6][t]+ls[7][t]));
        psq [blockIdx.x*64 + t] = ((lq[0][t]+lq[1][t]) + (lq[2][t]+lq[3][t]))
                                + ((lq[4][t]+lq[5][t]) + (lq[6][t]+lq[7][t]));
    }
}

// ============================================================
// 7. conv2 + affine2 + relu + max over k -> output (B,64,S).
// ============================================================
__global__ __launch_bounds__(256) void conv2max_kernel(
    const float* __restrict__ x, const float* __restrict__ aff1,
    const float* __restrict__ aff2, const float* __restrict__ W,
    const float* __restrict__ bias, float* __restrict__ outp)
{
    const int gt = blockIdx.x*256 + threadIdx.x;
    const int wv = gt >> 6;
    const int lane = gt & 63;
    const int base = wv * 64;
    float in[32];
    #pragma unroll
    for (int c = 0; c < 32; ++c) {
        const float r = x[(size_t)c*NSITES + base + lane];
        in[c] = fmaxf(fmaf(aff1[c], r, aff1[64 + c]), 0.f);
    }
    const int bs = (base + lane) >> 5;
    const int b = bs >> 10, s = bs & 1023;
    float* dst = outp + (size_t)b*64*NPOINT + s;
    for (int o = 0; o < 64; ++o) {
        float z = bias[o];
        #pragma unroll
        for (int c = 0; c < 32; ++c)
            z = fmaf(W[o*32+c], in[c], z);
        float y = fmaxf(fmaf(aff2[o], z, aff2[64 + o]), 0.f);
        #pragma unroll
        for (int off = 16; off >= 1; off >>= 1)
            y = fmaxf(y, __shfl_xor(y, off));
        if ((lane & 31) == 0)
            dst[(size_t)o*NPOINT] = y;
    }
}

// ============================================================
extern "C" void kernel_launch(void* const* d_in, const int* in_sizes, int n_in,
                              void* d_out, int out_size, void* d_ws, size_t ws_size,
                              hipStream_t stream) {
    (void)in_sizes; (void)n_in; (void)out_size; (void)ws_size;
    const float* xyz = (const float*)d_in[0];
    const float* pts = (const float*)d_in[1];
    const float* W0  = (const float*)d_in[2];
    const float* b0  = (const float*)d_in[3];
    const float* g0  = (const float*)d_in[4];
    const float* be0 = (const float*)d_in[5];
    const float* W1  = (const float*)d_in[6];
    const float* b1  = (const float*)d_in[7];
    const float* g1  = (const float*)d_in[8];
    const float* be1 = (const float*)d_in[9];
    const float* W2  = (const float*)d_in[10];
    const float* b2  = (const float*)d_in[11];
    const float* g2  = (const float*)d_in[12];
    const float* be2 = (const float*)d_in[13];
    float* out = (float*)d_out;
    char* ws = (char*)d_ws;
    float* nxyz = (float*)(ws + 0);
    int*   gidx = (int*)  (ws + 196608);
    float* psum = (float*)(ws + 2293760);
    float* psq  = (float*)(ws + 2424832);
    float* aff0 = (float*)(ws + 2555904);
    float* aff1 = (float*)(ws + 2556416);
    float* aff2 = (float*)(ws + 2556928);
    float* xbuf = (float*)(ws + 2557440);

    fps_kernel <<<16,  512, 0, stream>>>(xyz, nxyz, out);
    ball_kernel<<<256, 256, 0, stream>>>(xyz, nxyz, gidx);

    conv0s_kernel<<<512, 256, 0, stream>>>(xyz, pts, gidx, nxyz, W0, b0,
                                           xbuf, psum, psq);
    fold_kernel<<<1, 256, 0, stream>>>(g0, be0, psum, psq, aff0, 32);

    conv1s_kernel<<<512, 256, 0, stream>>>(xbuf, xbuf, aff0, W1, b1, psum, psq);
    fold_kernel<<<1, 256, 0, stream>>>(g1, be1, psum, psq, aff1, 32);

    conv2stats_kernel<<<512, 512, 0, stream>>>(xbuf, aff1, W2, b2, psum, psq);
    fold_kernel<<<1, 256, 0, stream>>>(g2, be2, psum, psq, aff2, 64);

    conv2max_kernel<<<2048, 256, 0, stream>>>(xbuf, aff1, aff2, W2, b2,
                                              out + 49152);
}

// Round 11
// 982.340 us; speedup vs baseline: 1.4142x; 1.0906x over previous
//
#include <hip/hip_runtime.h>

#define BATCH   16
#define NPTS    4096
#define NPOINT  1024
#define NSAMPLE 32
#define NSITES  (BATCH*NPOINT*NSAMPLE)   // 524288

typedef float f32x2 __attribute__((ext_vector_type(2)));

// ---------------- workspace layout (bytes) ----------------
// nxyz : 0        (196608)
// gidx : 196608   (2097152)
// psum : 2293760  (512*64*4 = 131072)
// psq  : 2424832  (131072)
// aff0 : 2555904  (128 f = 512)   aff = {a[64], c[64]}: act = relu(a*x+c)
// aff1 : 2556416  (512)
// aff2 : 2556928  (512)
// xbuf : 2557440  (64 MB)  -> total ~69.7 MB

// ---------------- DPP wave-64 max (f32), broadcast via readlane ----------
__device__ __forceinline__ float wave_max_bcast(float x) {
    int v = __float_as_int(x);
    int t;
    t = __builtin_amdgcn_update_dpp(v, v, 0x111, 0xf, 0xf, false);  // row_shr:1
    v = __float_as_int(fmaxf(__int_as_float(v), __int_as_float(t)));
    t = __builtin_amdgcn_update_dpp(v, v, 0x112, 0xf, 0xf, false);  // row_shr:2
    v = __float_as_int(fmaxf(__int_as_float(v), __int_as_float(t)));
    t = __builtin_amdgcn_update_dpp(v, v, 0x114, 0xf, 0xf, false);  // row_shr:4
    v = __float_as_int(fmaxf(__int_as_float(v), __int_as_float(t)));
    t = __builtin_amdgcn_update_dpp(v, v, 0x118, 0xf, 0xf, false);  // row_shr:8
    v = __float_as_int(fmaxf(__int_as_float(v), __int_as_float(t)));
    t = __builtin_amdgcn_update_dpp(v, v, 0x142, 0xa, 0xf, false);  // row_bcast:15
    v = __float_as_int(fmaxf(__int_as_float(v), __int_as_float(t)));
    t = __builtin_amdgcn_update_dpp(v, v, 0x143, 0xc, 0xf, false);  // row_bcast:31
    v = __float_as_int(fmaxf(__int_as_float(v), __int_as_float(t)));
    return __int_as_float(__builtin_amdgcn_readlane(v, 63));
}

// ============================================================
// 1. FPS: one block/batch, 512 threads, 8 CONTIGUOUS pts/thread in registers.
//    Structure = r5's proven 648us kernel EXACTLY (pre-barrier val+idx tree,
//    DPP wave max, ballot lowest-lane, winner u64 key; post-barrier 8-key
//    uniform read + register u64 tree + sx[far] coord reads). r6-r10
//    established all reduce restructures are neutral-to-worse.
//    ONE change: distance update uses native float2 (ext_vector) arithmetic
//    so LLVM selects v_pk_add_f32/v_pk_mul_f32 (dual-issue f32, per-component
//    IEEE-rn == scalar bits; r6's regression was asm marshalling, not pk).
//    72 -> ~40 VALU/thread/iter. fminf stays scalar (no pk_min).
//    Distance math bit-matches reference (validated rounds 2-10).
// ============================================================
__global__ __launch_bounds__(512, 1) void fps_kernel(
    const float* __restrict__ xyz,   // (B,3,N)
    float* __restrict__ nxyz,        // (B,S,3)
    float* __restrict__ out0)        // (B,3,S)
{
    __shared__ float sx[NPTS], sy[NPTS], sz[NPTS];
    __shared__ int   s_sel[NPOINT];
    __shared__ unsigned long long redK[2][8];

    const int b = blockIdx.x;
    const int t = threadIdx.x;
    const int wave = t >> 6, lane = t & 63;
    const float* xb = xyz + (size_t)b * 3 * NPTS;

    for (int i = t; i < NPTS; i += 512) {
        sx[i] = xb[i]; sy[i] = xb[NPTS+i]; sz[i] = xb[2*NPTS+i];
    }
    __syncthreads();

    const int base = t * 8;
    // j = 2k + comp: comp 0 -> .x, comp 1 -> .y  (contiguous global indices)
    f32x2 px[4], py[4], pz[4], dd[4];
    #pragma unroll
    for (int k = 0; k < 4; ++k) {
        px[k] = (f32x2){ sx[base+2*k], sx[base+2*k+1] };
        py[k] = (f32x2){ sy[base+2*k], sy[base+2*k+1] };
        pz[k] = (f32x2){ sz[base+2*k], sz[base+2*k+1] };
        dd[k] = (f32x2){ 1e10f, 1e10f };
    }

    int far = 0;
    float cx = sx[0], cy = sy[0], cz = sz[0];
    for (int it = 0; it < NPOINT; ++it) {
        if (t == 0) s_sel[it] = far;
        const f32x2 vcx = (f32x2){cx, cx};
        const f32x2 vcy = (f32x2){cy, cy};
        const f32x2 vcz = (f32x2){cz, cz};
        #pragma unroll
        for (int k = 0; k < 4; ++k) {
            const f32x2 dx = px[k] - vcx;          // v_pk_add (neg mod), exact
            const f32x2 dy = py[k] - vcy;
            const f32x2 dz = pz[k] - vcz;
            const f32x2 s  = (dx*dx + dy*dy) + dz*dz;   // pk mul/add, ref order
            dd[k].x = fminf(dd[k].x, s.x);
            dd[k].y = fminf(dd[k].y, s.y);
        }
        // per-thread first-max tree (strict > : earlier index wins ties)
        const float d0 = dd[0].x, d1 = dd[0].y, d2 = dd[1].x, d3 = dd[1].y;
        const float d4 = dd[2].x, d5 = dd[2].y, d6 = dd[3].x, d7 = dd[3].y;
        float tv0, tv1, tv2, tv3; int ti0, ti1, ti2, ti3;
        { bool c = d1 > d0; tv0 = c ? d1 : d0; ti0 = c ? 1 : 0; }
        { bool c = d3 > d2; tv1 = c ? d3 : d2; ti1 = c ? 3 : 2; }
        { bool c = d5 > d4; tv2 = c ? d5 : d4; ti2 = c ? 5 : 4; }
        { bool c = d7 > d6; tv3 = c ? d7 : d6; ti3 = c ? 7 : 6; }
        float nv0, nv1; int ni0, ni1;
        { bool c = tv1 > tv0; nv0 = c ? tv1 : tv0; ni0 = c ? ti1 : ti0; }
        { bool c = tv3 > tv2; nv1 = c ? tv3 : tv2; ni1 = c ? ti3 : ti2; }
        float bm; int bj;
        { bool c = nv1 > nv0; bm = c ? nv1 : nv0; bj = c ? ni1 : ni0; }
        // DPP wave max, uniform broadcast
        const float M = wave_max_bcast(bm);
        // lowest matching lane == smallest global index (contiguous ownership)
        const unsigned long long mask = __ballot(bm == M);
        const int wl = __ffsll((long long)mask) - 1;
        const int par = it & 1;
        if (lane == wl) {
            const unsigned idxg = (unsigned)(base + bj);
            redK[par][wave] = ((unsigned long long)__float_as_uint(M) << 32)
                              | (unsigned)(~idxg);
        }
        __syncthreads();
        // register compare tree over the 8 wave keys (uniform LDS broadcasts)
        const unsigned long long k0 = redK[par][0], k1 = redK[par][1];
        const unsigned long long k2 = redK[par][2], k3 = redK[par][3];
        const unsigned long long k4 = redK[par][4], k5 = redK[par][5];
        const unsigned long long k6 = redK[par][6], k7 = redK[par][7];
        const unsigned long long a0 = (k1 > k0) ? k1 : k0;
        const unsigned long long a1 = (k3 > k2) ? k3 : k2;
        const unsigned long long a2 = (k5 > k4) ? k5 : k4;
        const unsigned long long a3 = (k7 > k6) ? k7 : k6;
        const unsigned long long b0_ = (a1 > a0) ? a1 : a0;
        const unsigned long long b1_ = (a3 > a2) ? a3 : a2;
        const unsigned long long km  = (b1_ > b0_) ? b1_ : b0_;
        far = (int)((~(unsigned)km) & (NPTS-1));
        cx = sx[far]; cy = sy[far]; cz = sz[far];
    }
    __syncthreads();
    for (int s = t; s < NPOINT; s += 512) {
        const int id = s_sel[s];
        const float x = sx[id], y = sy[id], z = sz[id];
        nxyz[((size_t)b*NPOINT + s)*3 + 0] = x;
        nxyz[((size_t)b*NPOINT + s)*3 + 1] = y;
        nxyz[((size_t)b*NPOINT + s)*3 + 2] = z;
        out0[(size_t)b*3*NPOINT + 0*NPOINT + s] = x;
        out0[(size_t)b*3*NPOINT + 1*NPOINT + s] = y;
        out0[(size_t)b*3*NPOINT + 2*NPOINT + s] = z;
    }
}

// ============================================================
// 2. Ball query (validated bit-exact rounds 2-10 — unchanged).
// ============================================================
__global__ __launch_bounds__(256) void ball_kernel(
    const float* __restrict__ xyz, const float* __restrict__ nxyz,
    int* __restrict__ gidx)
{
    __shared__ float sx[NPTS], sy[NPTS], sz[NPTS];
    const int b  = blockIdx.x >> 4;
    const int sg = blockIdx.x & 15;
    const int t = threadIdx.x;
    const int wave = t >> 6, lane = t & 63;
    const float* xb = xyz + (size_t)b * 3 * NPTS;
    for (int i = t; i < NPTS; i += 256) {
        sx[i] = xb[i]; sy[i] = xb[NPTS+i]; sz[i] = xb[2*NPTS+i];
    }
    __syncthreads();
    const unsigned long long lt = (1ull << lane) - 1ull;

    for (int q = wave; q < 64; q += 4) {
        const int s = sg*64 + q;
        const size_t bs = (size_t)b*NPOINT + s;
        const float cx = nxyz[bs*3+0], cy = nxyz[bs*3+1], cz = nxyz[bs*3+2];
        const float ss = __fadd_rn(__fadd_rn(__fmul_rn(cx,cx), __fmul_rn(cy,cy)),
                                   __fmul_rn(cz,cz));
        int* out = gidx + bs*NSAMPLE;
        int cnt = 0;
        int firstIdx = NPTS;
        for (int ch = 0; ch < NPTS/64 && cnt < NSAMPLE; ++ch) {
            const int pi = ch*64 + lane;
            const float qx = sx[pi], qy = sy[pi], qz = sz[pi];
            const float dot = fmaf(cz, qz, fmaf(cy, qy, __fmul_rn(cx, qx)));
            const float sn  = __fadd_rn(__fadd_rn(__fmul_rn(qx,qx), __fmul_rn(qy,qy)),
                                        __fmul_rn(qz,qz));
            const float d   = __fadd_rn(__fadd_rn(__fmul_rn(-2.0f,dot), ss), sn);
            const bool pred = !(d > 0.04f);
            const unsigned long long m = __ballot(pred);
            if (pred) {
                const int pos = cnt + __popcll(m & lt);
                if (pos == 0) firstIdx = pi;
                if (pos < NSAMPLE) out[pos] = pi;
            }
            cnt += (int)__popcll(m);
        }
        if (cnt < NSAMPLE) {
            #pragma unroll
            for (int off = 32; off >= 1; off >>= 1) {
                const int oi = __shfl_xor(firstIdx, off);
                firstIdx = (oi < firstIdx) ? oi : firstIdx;
            }
            for (int p = cnt + lane; p < NSAMPLE; p += 64) out[p] = firstIdx;
        }
    }
}

// ---------------- feature gather (9 ch per site) ----------------
__device__ __forceinline__ void gather_feat(
    const float* __restrict__ xyz, const float* __restrict__ pts,
    const int* __restrict__ gidx, const float* __restrict__ nxyz,
    int v, float4 f[9])
{
    const int site = v * 4;
    const int bs = site >> 5;
    const int b  = bs >> 10;
    const int4 idx = *reinterpret_cast<const int4*>(gidx + site);
    const float* xb = xyz + (size_t)b*3*NPTS;
    const float* pb = pts + (size_t)b*6*NPTS;
    const float cx = nxyz[(size_t)bs*3+0];
    const float cy = nxyz[(size_t)bs*3+1];
    const float cz = nxyz[(size_t)bs*3+2];
    f[0] = make_float4(xb[idx.x]-cx, xb[idx.y]-cx, xb[idx.z]-cx, xb[idx.w]-cx);
    f[1] = make_float4(xb[NPTS+idx.x]-cy, xb[NPTS+idx.y]-cy, xb[NPTS+idx.z]-cy, xb[NPTS+idx.w]-cy);
    f[2] = make_float4(xb[2*NPTS+idx.x]-cz, xb[2*NPTS+idx.y]-cz, xb[2*NPTS+idx.z]-cz, xb[2*NPTS+idx.w]-cz);
    #pragma unroll
    for (int c = 0; c < 6; ++c)
        f[3+c] = make_float4(pb[c*NPTS+idx.x], pb[c*NPTS+idx.y], pb[c*NPTS+idx.z], pb[c*NPTS+idx.w]);
}

// ============================================================
// 3. conv0: ONE gather pass -> raw conv0 (W0,b0) stored + stats partials.
// ============================================================
__global__ __launch_bounds__(256) void conv0s_kernel(
    const float* __restrict__ xyz, const float* __restrict__ pts,
    const int* __restrict__ gidx, const float* __restrict__ nxyz,
    const float* __restrict__ W, const float* __restrict__ bias,
    float* __restrict__ xout, float* __restrict__ psum, float* __restrict__ psq)
{
    const int t = threadIdx.x;
    const int v = blockIdx.x*256 + t;        // 512 blocks -> v < 131072
    const int site = v * 4;
    float4 f[9];
    gather_feat(xyz, pts, gidx, nxyz, v, f);
    float acc[32], accq[32];
    #pragma unroll
    for (int o = 0; o < 32; ++o) {
        const float bb = bias[o];
        float4 y = make_float4(bb,bb,bb,bb);
        #pragma unroll
        for (int c = 0; c < 9; ++c) {
            const float w = W[o*9+c];
            y.x = fmaf(w, f[c].x, y.x); y.y = fmaf(w, f[c].y, y.y);
            y.z = fmaf(w, f[c].z, y.z); y.w = fmaf(w, f[c].w, y.w);
        }
        *reinterpret_cast<float4*>(xout + (size_t)o*NSITES + site) = y;  // RAW
        acc[o]  = (y.x + y.y) + (y.z + y.w);
        accq[o] = (y.x*y.x + y.y*y.y) + (y.z*y.z + y.w*y.w);
    }
    __shared__ float ls[4][32], lq[4][32];
    const int wave = t>>6, lane = t&63;
    #pragma unroll
    for (int o = 0; o < 32; ++o) {
        float s1 = acc[o], q1 = accq[o];
        #pragma unroll
        for (int off = 32; off >= 1; off >>= 1) {
            s1 += __shfl_xor(s1, off);
            q1 += __shfl_xor(q1, off);
        }
        if (lane == 0) { ls[wave][o] = s1; lq[wave][o] = q1; }
    }
    __syncthreads();
    if (t < 32) {
        psum[blockIdx.x*64 + t] = (ls[0][t]+ls[1][t]) + (ls[2][t]+ls[3][t]);
        psq [blockIdx.x*64 + t] = (lq[0][t]+lq[1][t]) + (lq[2][t]+lq[3][t]);
    }
}

// ============================================================
// 4. fold: partials -> mean/var -> affine {a, c}: act = relu(a*raw + c)
//    Parallel version: 256 threads, 4 parts/channel + LDS combine.
// ============================================================
__global__ void fold_kernel(
    const float* __restrict__ g, const float* __restrict__ be,
    const float* __restrict__ psum, const float* __restrict__ psq,
    float* __restrict__ aff, int Cout)
{
    __shared__ float ss[4][64], qq[4][64];
    const int t = threadIdx.x;           // 256
    const int ch = t & 63, part = t >> 6;
    float s = 0.f, q = 0.f;
    for (int i = part; i < 512; i += 4) {
        s += psum[i*64 + ch];
        q += psq [i*64 + ch];
    }
    ss[part][ch] = s; qq[part][ch] = q;
    __syncthreads();
    if (t < Cout) {
        s = (ss[0][t]+ss[1][t]) + (ss[2][t]+ss[3][t]);
        q = (qq[0][t]+qq[1][t]) + (qq[2][t]+qq[3][t]);
        const float invn = 1.0f / (float)NSITES;
        const float m = s * invn;
        float v2 = fmaxf(q * invn - m*m, 0.f);
        const float a = g[t] * rsqrtf(v2 + 1e-5f);
        aff[t]      = a;
        aff[64 + t] = fmaf(-m, a, be[t]);
    }
}

// ============================================================
// 5. conv1: read raw0, act0 = relu(a0*x+c0) on the fly, conv1 (W1,b1) ->
//    raw1 stored IN PLACE + stats partials.
// ============================================================
__global__ __launch_bounds__(256) void conv1s_kernel(
    const float* x, float* xout,
    const float* __restrict__ aff, const float* __restrict__ W,
    const float* __restrict__ bias,
    float* __restrict__ psum, float* __restrict__ psq)
{
    const int t = threadIdx.x;
    const int v = blockIdx.x*256 + t;
    const int site = v * 4;
    float4 in[32];
    #pragma unroll
    for (int c = 0; c < 32; ++c) {
        float4 r = *reinterpret_cast<const float4*>(x + (size_t)c*NSITES + site);
        const float a = aff[c], cc = aff[64 + c];
        in[c].x = fmaxf(fmaf(a, r.x, cc), 0.f);
        in[c].y = fmaxf(fmaf(a, r.y, cc), 0.f);
        in[c].z = fmaxf(fmaf(a, r.z, cc), 0.f);
        in[c].w = fmaxf(fmaf(a, r.w, cc), 0.f);
    }
    float acc[32], accq[32];
    #pragma unroll
    for (int o = 0; o < 32; ++o) {
        const float bb = bias[o];
        float4 y = make_float4(bb,bb,bb,bb);
        #pragma unroll
        for (int c = 0; c < 32; ++c) {
            const float w = W[o*32+c];
            y.x = fmaf(w, in[c].x, y.x); y.y = fmaf(w, in[c].y, y.y);
            y.z = fmaf(w, in[c].z, y.z); y.w = fmaf(w, in[c].w, y.w);
        }
        *reinterpret_cast<float4*>(xout + (size_t)o*NSITES + site) = y;  // RAW
        acc[o]  = (y.x + y.y) + (y.z + y.w);
        accq[o] = (y.x*y.x + y.y*y.y) + (y.z*y.z + y.w*y.w);
    }
    __shared__ float ls[4][32], lq[4][32];
    const int wave = t>>6, lane = t&63;
    #pragma unroll
    for (int o = 0; o < 32; ++o) {
        float s1 = acc[o], q1 = accq[o];
        #pragma unroll
        for (int off = 32; off >= 1; off >>= 1) {
            s1 += __shfl_xor(s1, off);
            q1 += __shfl_xor(q1, off);
        }
        if (lane == 0) { ls[wave][o] = s1; lq[wave][o] = q1; }
    }
    __syncthreads();
    if (t < 32) {
        psum[blockIdx.x*64 + t] = (ls[0][t]+ls[1][t]) + (ls[2][t]+ls[3][t]);
        psq [blockIdx.x*64 + t] = (lq[0][t]+lq[1][t]) + (lq[2][t]+lq[3][t]);
    }
}

// ============================================================
// 6. conv2 stats: SINGLE pass (r9-proven). 512 blocks x 512 threads x
//    2 sites/thread; acc[64] in registers. Reads raw1 once, act1 on the fly.
// ============================================================
__global__ __launch_bounds__(512, 1) void conv2stats_kernel(
    const float* __restrict__ x, const float* __restrict__ aff,
    const float* __restrict__ W, const float* __restrict__ bias,
    float* __restrict__ psum, float* __restrict__ psq)
{
    const int t = threadIdx.x;
    const int v = blockIdx.x*512 + t;        // 512 blocks -> v < 262144
    const int site = v * 2;
    float2 in[32];
    #pragma unroll
    for (int c = 0; c < 32; ++c) {
        const float2 r = *reinterpret_cast<const float2*>(x + (size_t)c*NSITES + site);
        const float a = aff[c], cc = aff[64 + c];
        in[c].x = fmaxf(fmaf(a, r.x, cc), 0.f);
        in[c].y = fmaxf(fmaf(a, r.y, cc), 0.f);
    }
    float acc[64], accq[64];
    #pragma unroll
    for (int o = 0; o < 64; ++o) {
        const float bb = bias[o];
        float yx = bb, yy = bb;
        #pragma unroll
        for (int c = 0; c < 32; ++c) {
            const float w = W[o*32+c];
            yx = fmaf(w, in[c].x, yx);
            yy = fmaf(w, in[c].y, yy);
        }
        acc[o]  = yx + yy;
        accq[o] = yx*yx + yy*yy;
    }
    __shared__ float ls[8][64], lq[8][64];
    const int wave = t>>6, lane = t&63;
    #pragma unroll
    for (int o = 0; o < 64; ++o) {
        float s1 = acc[o], q1 = accq[o];
        #pragma unroll
        for (int off = 32; off >= 1; off >>= 1) {
            s1 += __shfl_xor(s1, off);
            q1 += __shfl_xor(q1, off);
        }
        if (lane == 0) { ls[wave][o] = s1; lq[wave][o] = q1; }
    }
    __syncthreads();
    if (t < 64) {
        psum[blockIdx.x*64 + t] = ((ls[0][t]+ls[1][t]) + (ls[2][t]+ls[3][t]))
                                + ((ls[4][t]+ls[5][t]) + (ls[6][t]+ls[7][t]));
        psq [blockIdx.x*64 + t] = ((lq[0][t]+lq[1][t]) + (lq[2][t]+lq[3][t]))
                                + ((lq[4][t]+lq[5][t]) + (lq[6][t]+lq[7][t]));
    }
}

// ============================================================
// 7. conv2 + affine2 + relu + max over k -> output (B,64,S).
// ============================================================
__global__ __launch_bounds__(256) void conv2max_kernel(
    const float* __restrict__ x, const float* __restrict__ aff1,
    const float* __restrict__ aff2, const float* __restrict__ W,
    const float* __restrict__ bias, float* __restrict__ outp)
{
    const int gt = blockIdx.x*256 + threadIdx.x;
    const int wv = gt >> 6;
    const int lane = gt & 63;
    const int base = wv * 64;
    float in[32];
    #pragma unroll
    for (int c = 0; c < 32; ++c) {
        const float r = x[(size_t)c*NSITES + base + lane];
        in[c] = fmaxf(fmaf(aff1[c], r, aff1[64 + c]), 0.f);
    }
    const int bs = (base + lane) >> 5;
    const int b = bs >> 10, s = bs & 1023;
    float* dst = outp + (size_t)b*64*NPOINT + s;
    for (int o = 0; o < 64; ++o) {
        float z = bias[o];
        #pragma unroll
        for (int c = 0; c < 32; ++c)
            z = fmaf(W[o*32+c], in[c], z);
        float y = fmaxf(fmaf(aff2[o], z, aff2[64 + o]), 0.f);
        #pragma unroll
        for (int off = 16; off >= 1; off >>= 1)
            y = fmaxf(y, __shfl_xor(y, off));
        if ((lane & 31) == 0)
            dst[(size_t)o*NPOINT] = y;
    }
}

// ============================================================
extern "C" void kernel_launch(void* const* d_in, const int* in_sizes, int n_in,
                              void* d_out, int out_size, void* d_ws, size_t ws_size,
                              hipStream_t stream) {
    (void)in_sizes; (void)n_in; (void)out_size; (void)ws_size;
    const float* xyz = (const float*)d_in[0];
    const float* pts = (const float*)d_in[1];
    const float* W0  = (const float*)d_in[2];
    const float* b0  = (const float*)d_in[3];
    const float* g0  = (const float*)d_in[4];
    const float* be0 = (const float*)d_in[5];
    const float* W1  = (const float*)d_in[6];
    const float* b1  = (const float*)d_in[7];
    const float* g1  = (const float*)d_in[8];
    const float* be1 = (const float*)d_in[9];
    const float* W2  = (const float*)d_in[10];
    const float* b2  = (const float*)d_in[11];
    const float* g2  = (const float*)d_in[12];
    const float* be2 = (const float*)d_in[13];
    float* out = (float*)d_out;
    char* ws = (char*)d_ws;
    float* nxyz = (float*)(ws + 0);
    int*   gidx = (int*)  (ws + 196608);
    float* psum = (float*)(ws + 2293760);
    float* psq  = (float*)(ws + 2424832);
    float* aff0 = (float*)(ws + 2555904);
    float* aff1 = (float*)(ws + 2556416);
    float* aff2 = (float*)(ws + 2556928);
    float* xbuf = (float*)(ws + 2557440);

    fps_kernel <<<16,  512, 0, stream>>>(xyz, nxyz, out);
    ball_kernel<<<256, 256, 0, stream>>>(xyz, nxyz, gidx);

    conv0s_kernel<<<512, 256, 0, stream>>>(xyz, pts, gidx, nxyz, W0, b0,
                                           xbuf, psum, psq);
    fold_kernel<<<1, 256, 0, stream>>>(g0, be0, psum, psq, aff0, 32);

    conv1s_kernel<<<512, 256, 0, stream>>>(xbuf, xbuf, aff0, W1, b1, psum, psq);
    fold_kernel<<<1, 256, 0, stream>>>(g1, be1, psum, psq, aff1, 32);

    conv2stats_kernel<<<512, 512, 0, stream>>>(xbuf, aff1, W2, b2, psum, psq);
    fold_kernel<<<1, 256, 0, stream>>>(g2, be2, psum, psq, aff2, 64);

    conv2max_kernel<<<2048, 256, 0, stream>>>(xbuf, aff1, aff2, W2, b2,
                                              out + 49152);
}